// Round 5
// baseline (425.402 us; speedup 1.0000x reference)
//
#include <hip/hip_runtime.h>
#include <cstdint>
#include <cstddef>

// Problem constants (from reference): B=2, T=2048, C=1024, H=16, hs=64
// Harness dtypes: inputs fp32, output fp32; internal compute bf16 MFMA.
#define BB 2
#define TT 2048
#define CC 1024
#define HH 16
#define HS 64
#define MM (BB*TT)      // 4096 rows
#define N1 (3*CC)       // 3072 qkv cols

// P-scratch row stride in elements (80 B/row: 16B-aligned, 2-way banks only)
#define PST2 40

// q prescale: hs^-0.5 * log2(e)  -> softmax_e(s) == softmax_2(s*log2e)
#define QSCALE 0.1803368801111243f

typedef __bf16 bf16_t;
typedef bf16_t bf16x8 __attribute__((ext_vector_type(8)));
typedef float  floatx4 __attribute__((ext_vector_type(4)));

__device__ __forceinline__ bf16_t f2bf(float f) {
    uint32_t u = __builtin_bit_cast(uint32_t, f);
    u += 0x7FFFu + ((u >> 16) & 1u);   // round-to-nearest-even
    unsigned short s = (unsigned short)(u >> 16);
    return __builtin_bit_cast(bf16_t, s);
}

__device__ __forceinline__ void load_lds16(const bf16_t* g, bf16_t* l) {
    __builtin_amdgcn_global_load_lds((__attribute__((address_space(1))) void*)g,
                                     (__attribute__((address_space(3))) void*)l,
                                     16, 0, 0);
}

// ---------------------------------------------------------------- pack x
__global__ __launch_bounds__(256) void k_pack(const float* __restrict__ src,
                                              bf16_t* __restrict__ dst) {
    size_t i = ((size_t)blockIdx.x * 256 + threadIdx.x) * 8;
    float4 a = *(const float4*)(src + i);
    float4 b = *(const float4*)(src + i + 4);
    bf16x8 o;
    o[0] = f2bf(a.x); o[1] = f2bf(a.y); o[2] = f2bf(a.z); o[3] = f2bf(a.w);
    o[4] = f2bf(b.x); o[5] = f2bf(b.y); o[6] = f2bf(b.z); o[7] = f2bf(b.w);
    *(bf16x8*)(dst + i) = o;
}

// ---------------------------------------------------------------- transpose+cvt
__global__ __launch_bounds__(256) void k_transpose(const float* __restrict__ src,
                                                   bf16_t* __restrict__ dst,
                                                   int R, int Ccol) {
    __shared__ bf16_t tile[32][33];
    int c0 = blockIdx.x * 32, r0 = blockIdx.y * 32;
    int tx = threadIdx.x, ty = threadIdx.y;
    for (int i = ty; i < 32; i += 8)
        tile[i][tx] = f2bf(src[(size_t)(r0 + i) * Ccol + c0 + tx]);
    __syncthreads();
    for (int i = ty; i < 32; i += 8)
        dst[(size_t)(c0 + i) * R + r0 + tx] = tile[tx][i];
}

// ---------------------------------------------------------------- GEMM core
__device__ __forceinline__ void gemm_core(const bf16_t* __restrict__ A,
                                          const bf16_t* __restrict__ Bt,
                                          bf16_t* As, bf16_t* Bs,
                                          int m0, int n0, int K,
                                          floatx4 acc[4][4]) {
    const int tid = threadIdx.x;
    const int wave = tid >> 6, lane = tid & 63;
    const int quad = lane >> 4, lrow = lane & 15;
    const int wm = wave >> 1, wn = wave & 1;
    const int lsub = lane >> 2;
    const int kc = lane & 3;

    for (int kk = 0; kk < K; kk += 32) {
        for (int s = 0; s < 2; ++s) {
            int rg = wave * 2 + s;
            const bf16_t* ga = A  + (size_t)(m0 + rg * 16 + lsub) * K + kk + kc * 8;
            const bf16_t* gb = Bt + (size_t)(n0 + rg * 16 + lsub) * K + kk + kc * 8;
            load_lds16(ga, As + rg * 512);
            load_lds16(gb, Bs + rg * 512);
        }
        __syncthreads();
        bf16x8 af[4], bfr[4];
        for (int i = 0; i < 4; ++i)
            af[i] = *(const bf16x8*)(As + (wm * 64 + i * 16 + lrow) * 32 + quad * 8);
        for (int j = 0; j < 4; ++j)
            bfr[j] = *(const bf16x8*)(Bs + (wn * 64 + j * 16 + lrow) * 32 + quad * 8);
        for (int i = 0; i < 4; ++i)
            for (int j = 0; j < 4; ++j)
                acc[i][j] = __builtin_amdgcn_mfma_f32_16x16x32_bf16(af[i], bfr[j], acc[i][j], 0, 0, 0);
        __syncthreads();
    }
}

// ---------------------------------------------------------------- QKV GEMM
// q prescaled by QSCALE (hs^-0.5 * log2e); v scattered TRANSPOSED and with
// key-interleave permutation sigma(t%32)=(t&15)*2+((t>>4)&1) baked in, so the
// attention PV B-frags stay 16B-contiguous while P packs (k, k+16) pairs.
__global__ __launch_bounds__(256, 2) void k_gemm_qkv(const bf16_t* __restrict__ x,
                                                     const bf16_t* __restrict__ Wt,
                                                     bf16_t* __restrict__ qb,
                                                     bf16_t* __restrict__ kb,
                                                     bf16_t* __restrict__ vb) {
    __shared__ bf16_t As[128 * 32];
    __shared__ bf16_t Bs[128 * 32];
    const int m0 = blockIdx.y * 128, n0 = blockIdx.x * 128;
    floatx4 acc[4][4];
    for (int i = 0; i < 4; ++i)
        for (int j = 0; j < 4; ++j)
            acc[i][j] = floatx4{0.f, 0.f, 0.f, 0.f};
    gemm_core(x, Wt, As, Bs, m0, n0, CC, acc);

    const int tid = threadIdx.x, wave = tid >> 6, lane = tid & 63;
    const int quad = lane >> 4, lrow = lane & 15;
    const int wm = wave >> 1, wn = wave & 1;
    for (int i = 0; i < 4; ++i)
        for (int j = 0; j < 4; ++j) {
            int gn = n0 + wn * 64 + j * 16 + lrow;
            int which = gn >> 10, c = gn & 1023, h = c >> 6, d = c & 63;
            for (int r = 0; r < 4; ++r) {
                int gm = m0 + wm * 64 + i * 16 + quad * 4 + r;
                int b = gm >> 11, t = gm & 2047;
                float val = acc[i][j][r];
                if (which == 0)
                    qb[((size_t)(b * HH + h) * TT + t) * HS + d] = f2bf(val * QSCALE);
                else if (which == 1)
                    kb[((size_t)(b * HH + h) * TT + t) * HS + d] = f2bf(val);
                else {
                    int tp = (t & ~31) | (((t & 15) << 1) | ((t >> 4) & 1));
                    vb[((size_t)(b * HH + h) * HS + d) * TT + tp] = f2bf(val);
                }
            }
        }
}

// ---------------------------------------------------------------- attention
// One wave (64-thread block) per 32 queries. 32-key tiles. No-max base-2
// softmax (exact). Causal mask peeled: only the final (diagonal) tile is
// masked. P packed 2 keys/dword via v_perm into LDS (key-interleaved to
// match permuted V). Block-uniform SGPR bases + one int offset per stream.
// Grid order bh-fast (XCD = bh%8 partitions K/V into per-XCD L2).
__global__ __launch_bounds__(64) void k_attn(const bf16_t* __restrict__ qb,
                                             const bf16_t* __restrict__ kb,
                                             const bf16_t* __restrict__ vt,
                                             bf16_t* __restrict__ y) {
    __shared__ bf16_t Ps[32 * PST2];          // 2560 B, one wave per block
    const int lane = threadIdx.x;
    const int quad = lane >> 4, lrow = lane & 15;
    const int bh  = blockIdx.x & 31;          // b*H + h
    const int qt2 = 63 - (blockIdx.x >> 5);   // 32-query tile, longest first
    const int q0  = qt2 * 32;
    const int nt  = qt2 + 1;                  // # of 32-key tiles

    const bf16_t* Q  = qb + (size_t)bh * TT * HS;
    const bf16_t* K0 = kb + (size_t)bh * TT * HS;     // rows j0+lrow
    const bf16_t* K1 = K0 + 16 * HS;                  // rows j0+16+lrow
    const bf16_t* V  = vt + (size_t)bh * HS * TT;
    const bf16_t* V0 = V;
    const bf16_t* V1 = V + 16 * TT;
    const bf16_t* V2 = V + 32 * TT;
    const bf16_t* V3 = V + 48 * TT;

    // Q fragments: 2 q-tiles x 2 k-chunks
    bf16x8 aq[2][2];
    for (int t = 0; t < 2; ++t)
        for (int c = 0; c < 2; ++c)
            aq[t][c] = *(const bf16x8*)(Q + (size_t)(q0 + t * 16 + lrow) * HS + c * 32 + quad * 8);

    floatx4 o[2][4];
    for (int t = 0; t < 2; ++t)
        for (int dc = 0; dc < 4; ++dc) o[t][dc] = floatx4{0.f, 0.f, 0.f, 0.f};
    float lsum[2][4] = {{0.f,0.f,0.f,0.f},{0.f,0.f,0.f,0.f}};

    int koff = (lrow * HS + quad * 8) * 2;    // bytes; +4096/iter
    int voff = (lrow * TT + quad * 8) * 2;    // bytes; +64/iter

    // preload K tile 0
    bf16x8 bk0 = *(const bf16x8*)((const char*)K0 + koff);
    bf16x8 bk1 = *(const bf16x8*)((const char*)K0 + koff + 64);
    bf16x8 bk2 = *(const bf16x8*)((const char*)K1 + koff);
    bf16x8 bk3 = *(const bf16x8*)((const char*)K1 + koff + 64);

    uint32_t* P32 = (uint32_t*)Ps;
    const int wrow0 = quad * 4;               // write rows wrow0..wrow0+3 (+16)

    for (int t = 0; t < nt - 1; ++t) {
        // QK^T (16 MFMA-equiv work, 8 instrs)
        floatx4 s00 = floatx4{0.f,0.f,0.f,0.f}, s01 = s00, s10 = s00, s11 = s00;
        s00 = __builtin_amdgcn_mfma_f32_16x16x32_bf16(aq[0][0], bk0, s00, 0, 0, 0);
        s00 = __builtin_amdgcn_mfma_f32_16x16x32_bf16(aq[0][1], bk1, s00, 0, 0, 0);
        s01 = __builtin_amdgcn_mfma_f32_16x16x32_bf16(aq[0][0], bk2, s01, 0, 0, 0);
        s01 = __builtin_amdgcn_mfma_f32_16x16x32_bf16(aq[0][1], bk3, s01, 0, 0, 0);
        s10 = __builtin_amdgcn_mfma_f32_16x16x32_bf16(aq[1][0], bk0, s10, 0, 0, 0);
        s10 = __builtin_amdgcn_mfma_f32_16x16x32_bf16(aq[1][1], bk1, s10, 0, 0, 0);
        s11 = __builtin_amdgcn_mfma_f32_16x16x32_bf16(aq[1][0], bk2, s11, 0, 0, 0);
        s11 = __builtin_amdgcn_mfma_f32_16x16x32_bf16(aq[1][1], bk3, s11, 0, 0, 0);

        // prefetch K tile t+1 (t+1 <= nt-1 always valid)
        koff += 4096;
        bk0 = *(const bf16x8*)((const char*)K0 + koff);
        bk1 = *(const bf16x8*)((const char*)K0 + koff + 64);
        bk2 = *(const bf16x8*)((const char*)K1 + koff);
        bk3 = *(const bf16x8*)((const char*)K1 + koff + 64);

        // V frags for tile t (permuted key order matches P pack)
        bf16x8 bv0 = *(const bf16x8*)((const char*)V0 + voff);
        bf16x8 bv1 = *(const bf16x8*)((const char*)V1 + voff);
        bf16x8 bv2 = *(const bf16x8*)((const char*)V2 + voff);
        bf16x8 bv3 = *(const bf16x8*)((const char*)V3 + voff);
        voff += 64;

        // exp2 (no mask: all keys here are strictly below the query band),
        // pack pairs (key, key+16) -> one dword, write to LDS
        for (int r = 0; r < 4; ++r) {
            float e00 = __builtin_amdgcn_exp2f(s00[r]);
            float e01 = __builtin_amdgcn_exp2f(s01[r]);
            float e10 = __builtin_amdgcn_exp2f(s10[r]);
            float e11 = __builtin_amdgcn_exp2f(s11[r]);
            lsum[0][r] += e00 + e01;
            lsum[1][r] += e10 + e11;
            uint32_t pk0 = __builtin_amdgcn_perm(
                __builtin_bit_cast(uint32_t, e01) + 0x8000u,
                __builtin_bit_cast(uint32_t, e00) + 0x8000u, 0x07060302u);
            uint32_t pk1 = __builtin_amdgcn_perm(
                __builtin_bit_cast(uint32_t, e11) + 0x8000u,
                __builtin_bit_cast(uint32_t, e10) + 0x8000u, 0x07060302u);
            P32[(wrow0 + r) * 20 + lrow]      = pk0;
            P32[(wrow0 + r + 16) * 20 + lrow] = pk1;
        }
        asm volatile("s_waitcnt lgkmcnt(0)" ::: "memory");

        // PV
        bf16x8 pa0 = *(const bf16x8*)(Ps + (size_t)lrow * PST2 + quad * 8);
        bf16x8 pa1 = *(const bf16x8*)(Ps + (size_t)(16 + lrow) * PST2 + quad * 8);
        o[0][0] = __builtin_amdgcn_mfma_f32_16x16x32_bf16(pa0, bv0, o[0][0], 0, 0, 0);
        o[0][1] = __builtin_amdgcn_mfma_f32_16x16x32_bf16(pa0, bv1, o[0][1], 0, 0, 0);
        o[0][2] = __builtin_amdgcn_mfma_f32_16x16x32_bf16(pa0, bv2, o[0][2], 0, 0, 0);
        o[0][3] = __builtin_amdgcn_mfma_f32_16x16x32_bf16(pa0, bv3, o[0][3], 0, 0, 0);
        o[1][0] = __builtin_amdgcn_mfma_f32_16x16x32_bf16(pa1, bv0, o[1][0], 0, 0, 0);
        o[1][1] = __builtin_amdgcn_mfma_f32_16x16x32_bf16(pa1, bv1, o[1][1], 0, 0, 0);
        o[1][2] = __builtin_amdgcn_mfma_f32_16x16x32_bf16(pa1, bv2, o[1][2], 0, 0, 0);
        o[1][3] = __builtin_amdgcn_mfma_f32_16x16x32_bf16(pa1, bv3, o[1][3], 0, 0, 0);
    }

    // ---- final (diagonal) tile: keys q0..q0+31, triangular mask
    {
        floatx4 s00 = floatx4{0.f,0.f,0.f,0.f}, s01 = s00, s10 = s00, s11 = s00;
        s00 = __builtin_amdgcn_mfma_f32_16x16x32_bf16(aq[0][0], bk0, s00, 0, 0, 0);
        s00 = __builtin_amdgcn_mfma_f32_16x16x32_bf16(aq[0][1], bk1, s00, 0, 0, 0);
        s01 = __builtin_amdgcn_mfma_f32_16x16x32_bf16(aq[0][0], bk2, s01, 0, 0, 0);
        s01 = __builtin_amdgcn_mfma_f32_16x16x32_bf16(aq[0][1], bk3, s01, 0, 0, 0);
        s10 = __builtin_amdgcn_mfma_f32_16x16x32_bf16(aq[1][0], bk0, s10, 0, 0, 0);
        s10 = __builtin_amdgcn_mfma_f32_16x16x32_bf16(aq[1][1], bk1, s10, 0, 0, 0);
        s11 = __builtin_amdgcn_mfma_f32_16x16x32_bf16(aq[1][0], bk2, s11, 0, 0, 0);
        s11 = __builtin_amdgcn_mfma_f32_16x16x32_bf16(aq[1][1], bk3, s11, 0, 0, 0);

        bf16x8 bv0 = *(const bf16x8*)((const char*)V0 + voff);
        bf16x8 bv1 = *(const bf16x8*)((const char*)V1 + voff);
        bf16x8 bv2 = *(const bf16x8*)((const char*)V2 + voff);
        bf16x8 bv3 = *(const bf16x8*)((const char*)V3 + voff);

        for (int r = 0; r < 4; ++r) {
            bool keep = lrow <= quad * 4 + r;   // col<=row within 16x16
            // tile0: keys 0..15 triangular, keys 16..31 all masked
            float e00 = keep ? __builtin_amdgcn_exp2f(s00[r]) : 0.f;
            float e01 = 0.f; (void)s01;
            // tile1: keys 0..15 all valid, keys 16..31 triangular
            float e10 = __builtin_amdgcn_exp2f(s10[r]);
            float e11 = keep ? __builtin_amdgcn_exp2f(s11[r]) : 0.f;
            lsum[0][r] += e00 + e01;
            lsum[1][r] += e10 + e11;
            uint32_t pk0 = __builtin_amdgcn_perm(
                __builtin_bit_cast(uint32_t, e01) + 0x8000u,
                __builtin_bit_cast(uint32_t, e00) + 0x8000u, 0x07060302u);
            uint32_t pk1 = __builtin_amdgcn_perm(
                __builtin_bit_cast(uint32_t, e11) + 0x8000u,
                __builtin_bit_cast(uint32_t, e10) + 0x8000u, 0x07060302u);
            P32[(wrow0 + r) * 20 + lrow]      = pk0;
            P32[(wrow0 + r + 16) * 20 + lrow] = pk1;
        }
        asm volatile("s_waitcnt lgkmcnt(0)" ::: "memory");

        bf16x8 pa0 = *(const bf16x8*)(Ps + (size_t)lrow * PST2 + quad * 8);
        bf16x8 pa1 = *(const bf16x8*)(Ps + (size_t)(16 + lrow) * PST2 + quad * 8);
        o[0][0] = __builtin_amdgcn_mfma_f32_16x16x32_bf16(pa0, bv0, o[0][0], 0, 0, 0);
        o[0][1] = __builtin_amdgcn_mfma_f32_16x16x32_bf16(pa0, bv1, o[0][1], 0, 0, 0);
        o[0][2] = __builtin_amdgcn_mfma_f32_16x16x32_bf16(pa0, bv2, o[0][2], 0, 0, 0);
        o[0][3] = __builtin_amdgcn_mfma_f32_16x16x32_bf16(pa0, bv3, o[0][3], 0, 0, 0);
        o[1][0] = __builtin_amdgcn_mfma_f32_16x16x32_bf16(pa1, bv0, o[1][0], 0, 0, 0);
        o[1][1] = __builtin_amdgcn_mfma_f32_16x16x32_bf16(pa1, bv1, o[1][1], 0, 0, 0);
        o[1][2] = __builtin_amdgcn_mfma_f32_16x16x32_bf16(pa1, bv2, o[1][2], 0, 0, 0);
        o[1][3] = __builtin_amdgcn_mfma_f32_16x16x32_bf16(pa1, bv3, o[1][3], 0, 0, 0);
    }

    // l reduction (once per wave) + output
    const int b = bh >> 4, h = bh & 15;
    for (int t = 0; t < 2; ++t)
        for (int r = 0; r < 4; ++r) {
            float s = lsum[t][r];
            s += __shfl_xor(s, 1, 64);
            s += __shfl_xor(s, 2, 64);
            s += __shfl_xor(s, 4, 64);
            s += __shfl_xor(s, 8, 64);
            float inv = 1.0f / s;
            int q = q0 + t * 16 + quad * 4 + r;
            for (int dc = 0; dc < 4; ++dc)
                y[(size_t)(b * TT + q) * CC + h * HS + dc * 16 + lrow] = f2bf(o[t][dc][r] * inv);
        }
}

// ---------------------------------------------------------------- out GEMM (fp32 out + bias)
__global__ __launch_bounds__(256, 2) void k_gemm_out(const bf16_t* __restrict__ yin,
                                                     const bf16_t* __restrict__ Wt,
                                                     const float* __restrict__ bias,
                                                     float* __restrict__ out) {
    __shared__ bf16_t As[128 * 32];
    __shared__ bf16_t Bs[128 * 32];
    const int m0 = blockIdx.y * 128, n0 = blockIdx.x * 128;
    floatx4 acc[4][4];
    for (int i = 0; i < 4; ++i)
        for (int j = 0; j < 4; ++j)
            acc[i][j] = floatx4{0.f, 0.f, 0.f, 0.f};
    gemm_core(yin, Wt, As, Bs, m0, n0, CC, acc);

    const int tid = threadIdx.x, wave = tid >> 6, lane = tid & 63;
    const int quad = lane >> 4, lrow = lane & 15;
    const int wm = wave >> 1, wn = wave & 1;
    for (int i = 0; i < 4; ++i)
        for (int j = 0; j < 4; ++j) {
            int gn = n0 + wn * 64 + j * 16 + lrow;
            float bb = bias[gn];
            for (int r = 0; r < 4; ++r) {
                int gm = m0 + wm * 64 + i * 16 + quad * 4 + r;
                out[(size_t)gm * CC + gn] = acc[i][j][r] + bb;
            }
        }
}

// ---------------------------------------------------------------- launch
extern "C" void kernel_launch(void* const* d_in, const int* in_sizes, int n_in,
                              void* d_out, int out_size, void* d_ws, size_t ws_size,
                              hipStream_t stream) {
    (void)in_sizes; (void)n_in; (void)out_size; (void)ws_size;
    const float* x    = (const float*)d_in[0];  // [2,2048,1024] fp32
    const float* Wqkv = (const float*)d_in[1];  // [1024,3072]   fp32
    const float* Wout = (const float*)d_in[2];  // [1024,1024]   fp32
    const float* bout = (const float*)d_in[3];  // [1024]        fp32
    float* out = (float*)d_out;                 // [2,2048,1024] fp32

    bf16_t* xb  = (bf16_t*)d_ws;                        // [4096][1024]  8 MB
    bf16_t* Wt1 = xb + (size_t)MM * CC;                 // [3072][1024]  6 MB
    bf16_t* Wt2 = Wt1 + (size_t)N1 * CC;                // [1024][1024]  2 MB
    bf16_t* qb  = Wt2 + (size_t)CC * CC;                // [B,H,T,hs]    8 MB
    bf16_t* kb  = qb + (size_t)BB * HH * TT * HS;       // [B,H,T,hs]    8 MB
    bf16_t* vb  = kb + (size_t)BB * HH * TT * HS;       // [B,H,hs,T~]   8 MB (perm)
    bf16_t* yb  = vb + (size_t)BB * HH * TT * HS;       // [B,T,C] bf16  8 MB

    k_pack<<<dim3((size_t)MM * CC / (256 * 8)), 256, 0, stream>>>(x, xb);
    k_transpose<<<dim3(N1 / 32, CC / 32), dim3(32, 8), 0, stream>>>(Wqkv, Wt1, CC, N1);
    k_transpose<<<dim3(CC / 32, CC / 32), dim3(32, 8), 0, stream>>>(Wout, Wt2, CC, CC);
    k_gemm_qkv<<<dim3(N1 / 128, MM / 128), 256, 0, stream>>>(xb, Wt1, qb, kb, vb);
    k_attn<<<dim3(64 * 32), 64, 0, stream>>>(qb, kb, vb, yb);
    k_gemm_out<<<dim3(CC / 128, MM / 128), 256, 0, stream>>>(yb, Wt2, bout, out);
}

// Round 6
// 220.332 us; speedup vs baseline: 1.9307x; 1.9307x over previous
//
#include <hip/hip_runtime.h>
#include <cstdint>
#include <cstddef>

// Problem constants (from reference): B=2, T=2048, C=1024, H=16, hs=64
// Harness dtypes: inputs fp32, output fp32; internal compute bf16 MFMA.
#define BB 2
#define TT 2048
#define CC 1024
#define HH 16
#define HS 64
#define MM (BB*TT)      // 4096 rows
#define N1 (3*CC)       // 3072 qkv cols

// P-scratch row stride in elements (80 B/row)
#define PST2 40

// q prescale: hs^-0.5 * log2(e)  -> softmax_e(s) == softmax_2(s*log2e)
#define QSCALE 0.1803368801111243f

typedef __bf16 bf16_t;
typedef bf16_t bf16x8 __attribute__((ext_vector_type(8)));
typedef float  floatx4 __attribute__((ext_vector_type(4)));

__device__ __forceinline__ bf16_t f2bf(float f) {
    uint32_t u = __builtin_bit_cast(uint32_t, f);
    u += 0x7FFFu + ((u >> 16) & 1u);   // round-to-nearest-even
    unsigned short s = (unsigned short)(u >> 16);
    return __builtin_bit_cast(bf16_t, s);
}

__device__ __forceinline__ void load_lds16(const bf16_t* g, bf16_t* l) {
    __builtin_amdgcn_global_load_lds((__attribute__((address_space(1))) void*)g,
                                     (__attribute__((address_space(3))) void*)l,
                                     16, 0, 0);
}

// ---------------------------------------------------------------- pack x
__global__ __launch_bounds__(256) void k_pack(const float* __restrict__ src,
                                              bf16_t* __restrict__ dst) {
    size_t i = ((size_t)blockIdx.x * 256 + threadIdx.x) * 8;
    float4 a = *(const float4*)(src + i);
    float4 b = *(const float4*)(src + i + 4);
    bf16x8 o;
    o[0] = f2bf(a.x); o[1] = f2bf(a.y); o[2] = f2bf(a.z); o[3] = f2bf(a.w);
    o[4] = f2bf(b.x); o[5] = f2bf(b.y); o[6] = f2bf(b.z); o[7] = f2bf(b.w);
    *(bf16x8*)(dst + i) = o;
}

// ---------------------------------------------------------------- transpose+cvt
__global__ __launch_bounds__(256) void k_transpose(const float* __restrict__ src,
                                                   bf16_t* __restrict__ dst,
                                                   int R, int Ccol) {
    __shared__ bf16_t tile[32][33];
    int c0 = blockIdx.x * 32, r0 = blockIdx.y * 32;
    int tx = threadIdx.x, ty = threadIdx.y;
    for (int i = ty; i < 32; i += 8)
        tile[i][tx] = f2bf(src[(size_t)(r0 + i) * Ccol + c0 + tx]);
    __syncthreads();
    for (int i = ty; i < 32; i += 8)
        dst[(size_t)(c0 + i) * R + r0 + tx] = tile[tx][i];
}

// ---------------------------------------------------------------- GEMM core
__device__ __forceinline__ void gemm_core(const bf16_t* __restrict__ A,
                                          const bf16_t* __restrict__ Bt,
                                          bf16_t* As, bf16_t* Bs,
                                          int m0, int n0, int K,
                                          floatx4 acc[4][4]) {
    const int tid = threadIdx.x;
    const int wave = tid >> 6, lane = tid & 63;
    const int quad = lane >> 4, lrow = lane & 15;
    const int wm = wave >> 1, wn = wave & 1;
    const int lsub = lane >> 2;
    const int kc = lane & 3;

    for (int kk = 0; kk < K; kk += 32) {
        for (int s = 0; s < 2; ++s) {
            int rg = wave * 2 + s;
            const bf16_t* ga = A  + (size_t)(m0 + rg * 16 + lsub) * K + kk + kc * 8;
            const bf16_t* gb = Bt + (size_t)(n0 + rg * 16 + lsub) * K + kk + kc * 8;
            load_lds16(ga, As + rg * 512);
            load_lds16(gb, Bs + rg * 512);
        }
        __syncthreads();
        bf16x8 af[4], bfr[4];
        for (int i = 0; i < 4; ++i)
            af[i] = *(const bf16x8*)(As + (wm * 64 + i * 16 + lrow) * 32 + quad * 8);
        for (int j = 0; j < 4; ++j)
            bfr[j] = *(const bf16x8*)(Bs + (wn * 64 + j * 16 + lrow) * 32 + quad * 8);
        for (int i = 0; i < 4; ++i)
            for (int j = 0; j < 4; ++j)
                acc[i][j] = __builtin_amdgcn_mfma_f32_16x16x32_bf16(af[i], bfr[j], acc[i][j], 0, 0, 0);
        __syncthreads();
    }
}

// ---------------------------------------------------------------- QKV GEMM
// q prescaled by QSCALE; k AND v both written natural [B,H,T,hs] (contiguous
// 32B/quad chunks that fully tile 128B lines -> no write amplification).
// The sigma-permuted V^T the attention wants is produced by k_vperm.
__global__ __launch_bounds__(256, 2) void k_gemm_qkv(const bf16_t* __restrict__ x,
                                                     const bf16_t* __restrict__ Wt,
                                                     bf16_t* __restrict__ qb,
                                                     bf16_t* __restrict__ kb,
                                                     bf16_t* __restrict__ vn) {
    __shared__ bf16_t As[128 * 32];
    __shared__ bf16_t Bs[128 * 32];
    const int m0 = blockIdx.y * 128, n0 = blockIdx.x * 128;
    floatx4 acc[4][4];
    for (int i = 0; i < 4; ++i)
        for (int j = 0; j < 4; ++j)
            acc[i][j] = floatx4{0.f, 0.f, 0.f, 0.f};
    gemm_core(x, Wt, As, Bs, m0, n0, CC, acc);

    const int tid = threadIdx.x, wave = tid >> 6, lane = tid & 63;
    const int quad = lane >> 4, lrow = lane & 15;
    const int wm = wave >> 1, wn = wave & 1;
    for (int i = 0; i < 4; ++i)
        for (int j = 0; j < 4; ++j) {
            int gn = n0 + wn * 64 + j * 16 + lrow;
            int which = gn >> 10, c = gn & 1023, h = c >> 6, d = c & 63;
            for (int r = 0; r < 4; ++r) {
                int gm = m0 + wm * 64 + i * 16 + quad * 4 + r;
                int b = gm >> 11, t = gm & 2047;
                float val = acc[i][j][r];
                if (which == 0)
                    qb[((size_t)(b * HH + h) * TT + t) * HS + d] = f2bf(val * QSCALE);
                else if (which == 1)
                    kb[((size_t)(b * HH + h) * TT + t) * HS + d] = f2bf(val);
                else
                    vn[((size_t)(b * HH + h) * TT + t) * HS + d] = f2bf(val);
            }
        }
}

// ---------------------------------------------------------------- V permute
// vn[B,H,T,hs] -> vt[B,H,hs,T] with per-32 key interleave sigma(u)=(u&15)*2+(u>>4)
// baked in (sigma^-1(2a)=a, sigma^-1(2a+1)=a+16). LDS 64x64 tile; coalesced
// bf16x8 loads, packed-dword 128B-dense stores.
__global__ __launch_bounds__(256) void k_vperm(const bf16_t* __restrict__ vn,
                                               bf16_t* __restrict__ vt) {
    __shared__ bf16_t tile[64][72];   // +8 pad, rows 16B-aligned (144B stride)
    const int tid = threadIdx.x;
    const int bh = blockIdx.x & 31, tb = blockIdx.x >> 5;   // 64-key block
    const bf16_t* src = vn + ((size_t)bh * TT + tb * 64) * HS;

    for (int h = 0; h < 2; ++h) {
        int r = (tid >> 3) + h * 32;            // key row 0..63
        int c8 = (tid & 7) * 8;                 // d col chunk
        *(bf16x8*)(&tile[r][c8]) = *(const bf16x8*)(src + (size_t)r * HS + c8);
    }
    __syncthreads();

    bf16_t* dst = vt + (size_t)bh * HS * TT + tb * 64;
    const int a   = tid & 15;                   // pair index within 32-block
    const int blk = ((tid >> 4) & 1) * 32;      // which 32-block
    const int dg  = tid >> 5;                   // d group 0..7
    for (int k = 0; k < 8; ++k) {
        int d = dg * 8 + k;
        uint32_t lo = (uint32_t)__builtin_bit_cast(unsigned short, tile[blk + a][d]);
        uint32_t hi = (uint32_t)__builtin_bit_cast(unsigned short, tile[blk + a + 16][d]);
        *(uint32_t*)(dst + (size_t)d * TT + blk + 2 * a) = lo | (hi << 16);
    }
}

// ---------------------------------------------------------------- attention
// One wave (64-thread block) per 32 queries; 32-key tiles; no-max base-2
// softmax (exact); mask peeled to the diagonal tile; P packed 2 keys/dword
// via v_perm into LDS (key-interleaved to match permuted V); bh-fast grid
// order (XCD = bh%8 partitions K/V across per-XCD L2s).
__global__ __launch_bounds__(64) void k_attn(const bf16_t* __restrict__ qb,
                                             const bf16_t* __restrict__ kb,
                                             const bf16_t* __restrict__ vt,
                                             bf16_t* __restrict__ y) {
    __shared__ bf16_t Ps[32 * PST2];
    const int lane = threadIdx.x;
    const int quad = lane >> 4, lrow = lane & 15;
    const int bh  = blockIdx.x & 31;
    const int qt2 = 63 - (blockIdx.x >> 5);   // 32-query tile, longest first
    const int q0  = qt2 * 32;
    const int nt  = qt2 + 1;

    const bf16_t* Q  = qb + (size_t)bh * TT * HS;
    const bf16_t* K0 = kb + (size_t)bh * TT * HS;
    const bf16_t* K1 = K0 + 16 * HS;
    const bf16_t* V  = vt + (size_t)bh * HS * TT;
    const bf16_t* V0 = V;
    const bf16_t* V1 = V + 16 * TT;
    const bf16_t* V2 = V + 32 * TT;
    const bf16_t* V3 = V + 48 * TT;

    bf16x8 aq[2][2];
    for (int t = 0; t < 2; ++t)
        for (int c = 0; c < 2; ++c)
            aq[t][c] = *(const bf16x8*)(Q + (size_t)(q0 + t * 16 + lrow) * HS + c * 32 + quad * 8);

    floatx4 o[2][4];
    for (int t = 0; t < 2; ++t)
        for (int dc = 0; dc < 4; ++dc) o[t][dc] = floatx4{0.f, 0.f, 0.f, 0.f};
    float lsum[2][4] = {{0.f,0.f,0.f,0.f},{0.f,0.f,0.f,0.f}};

    int koff = (lrow * HS + quad * 8) * 2;
    int voff = (lrow * TT + quad * 8) * 2;

    bf16x8 bk0 = *(const bf16x8*)((const char*)K0 + koff);
    bf16x8 bk1 = *(const bf16x8*)((const char*)K0 + koff + 64);
    bf16x8 bk2 = *(const bf16x8*)((const char*)K1 + koff);
    bf16x8 bk3 = *(const bf16x8*)((const char*)K1 + koff + 64);

    uint32_t* P32 = (uint32_t*)Ps;
    const int wrow0 = quad * 4;

    for (int t = 0; t < nt - 1; ++t) {
        floatx4 s00 = floatx4{0.f,0.f,0.f,0.f}, s01 = s00, s10 = s00, s11 = s00;
        s00 = __builtin_amdgcn_mfma_f32_16x16x32_bf16(aq[0][0], bk0, s00, 0, 0, 0);
        s00 = __builtin_amdgcn_mfma_f32_16x16x32_bf16(aq[0][1], bk1, s00, 0, 0, 0);
        s01 = __builtin_amdgcn_mfma_f32_16x16x32_bf16(aq[0][0], bk2, s01, 0, 0, 0);
        s01 = __builtin_amdgcn_mfma_f32_16x16x32_bf16(aq[0][1], bk3, s01, 0, 0, 0);
        s10 = __builtin_amdgcn_mfma_f32_16x16x32_bf16(aq[1][0], bk0, s10, 0, 0, 0);
        s10 = __builtin_amdgcn_mfma_f32_16x16x32_bf16(aq[1][1], bk1, s10, 0, 0, 0);
        s11 = __builtin_amdgcn_mfma_f32_16x16x32_bf16(aq[1][0], bk2, s11, 0, 0, 0);
        s11 = __builtin_amdgcn_mfma_f32_16x16x32_bf16(aq[1][1], bk3, s11, 0, 0, 0);

        koff += 4096;
        bk0 = *(const bf16x8*)((const char*)K0 + koff);
        bk1 = *(const bf16x8*)((const char*)K0 + koff + 64);
        bk2 = *(const bf16x8*)((const char*)K1 + koff);
        bk3 = *(const bf16x8*)((const char*)K1 + koff + 64);

        bf16x8 bv0 = *(const bf16x8*)((const char*)V0 + voff);
        bf16x8 bv1 = *(const bf16x8*)((const char*)V1 + voff);
        bf16x8 bv2 = *(const bf16x8*)((const char*)V2 + voff);
        bf16x8 bv3 = *(const bf16x8*)((const char*)V3 + voff);
        voff += 64;

        for (int r = 0; r < 4; ++r) {
            float e00 = __builtin_amdgcn_exp2f(s00[r]);
            float e01 = __builtin_amdgcn_exp2f(s01[r]);
            float e10 = __builtin_amdgcn_exp2f(s10[r]);
            float e11 = __builtin_amdgcn_exp2f(s11[r]);
            lsum[0][r] += e00 + e01;
            lsum[1][r] += e10 + e11;
            uint32_t pk0 = __builtin_amdgcn_perm(
                __builtin_bit_cast(uint32_t, e01) + 0x8000u,
                __builtin_bit_cast(uint32_t, e00) + 0x8000u, 0x07060302u);
            uint32_t pk1 = __builtin_amdgcn_perm(
                __builtin_bit_cast(uint32_t, e11) + 0x8000u,
                __builtin_bit_cast(uint32_t, e10) + 0x8000u, 0x07060302u);
            P32[(wrow0 + r) * 20 + lrow]      = pk0;
            P32[(wrow0 + r + 16) * 20 + lrow] = pk1;
        }
        asm volatile("s_waitcnt lgkmcnt(0)" ::: "memory");

        bf16x8 pa0 = *(const bf16x8*)(Ps + (size_t)lrow * PST2 + quad * 8);
        bf16x8 pa1 = *(const bf16x8*)(Ps + (size_t)(16 + lrow) * PST2 + quad * 8);
        o[0][0] = __builtin_amdgcn_mfma_f32_16x16x32_bf16(pa0, bv0, o[0][0], 0, 0, 0);
        o[0][1] = __builtin_amdgcn_mfma_f32_16x16x32_bf16(pa0, bv1, o[0][1], 0, 0, 0);
        o[0][2] = __builtin_amdgcn_mfma_f32_16x16x32_bf16(pa0, bv2, o[0][2], 0, 0, 0);
        o[0][3] = __builtin_amdgcn_mfma_f32_16x16x32_bf16(pa0, bv3, o[0][3], 0, 0, 0);
        o[1][0] = __builtin_amdgcn_mfma_f32_16x16x32_bf16(pa1, bv0, o[1][0], 0, 0, 0);
        o[1][1] = __builtin_amdgcn_mfma_f32_16x16x32_bf16(pa1, bv1, o[1][1], 0, 0, 0);
        o[1][2] = __builtin_amdgcn_mfma_f32_16x16x32_bf16(pa1, bv2, o[1][2], 0, 0, 0);
        o[1][3] = __builtin_amdgcn_mfma_f32_16x16x32_bf16(pa1, bv3, o[1][3], 0, 0, 0);
    }

    // ---- final (diagonal) tile
    {
        floatx4 s00 = floatx4{0.f,0.f,0.f,0.f}, s01 = s00, s10 = s00, s11 = s00;
        s00 = __builtin_amdgcn_mfma_f32_16x16x32_bf16(aq[0][0], bk0, s00, 0, 0, 0);
        s00 = __builtin_amdgcn_mfma_f32_16x16x32_bf16(aq[0][1], bk1, s00, 0, 0, 0);
        s01 = __builtin_amdgcn_mfma_f32_16x16x32_bf16(aq[0][0], bk2, s01, 0, 0, 0);
        s01 = __builtin_amdgcn_mfma_f32_16x16x32_bf16(aq[0][1], bk3, s01, 0, 0, 0);
        s10 = __builtin_amdgcn_mfma_f32_16x16x32_bf16(aq[1][0], bk0, s10, 0, 0, 0);
        s10 = __builtin_amdgcn_mfma_f32_16x16x32_bf16(aq[1][1], bk1, s10, 0, 0, 0);
        s11 = __builtin_amdgcn_mfma_f32_16x16x32_bf16(aq[1][0], bk2, s11, 0, 0, 0);
        s11 = __builtin_amdgcn_mfma_f32_16x16x32_bf16(aq[1][1], bk3, s11, 0, 0, 0);

        bf16x8 bv0 = *(const bf16x8*)((const char*)V0 + voff);
        bf16x8 bv1 = *(const bf16x8*)((const char*)V1 + voff);
        bf16x8 bv2 = *(const bf16x8*)((const char*)V2 + voff);
        bf16x8 bv3 = *(const bf16x8*)((const char*)V3 + voff);

        for (int r = 0; r < 4; ++r) {
            bool keep = lrow <= quad * 4 + r;
            float e00 = keep ? __builtin_amdgcn_exp2f(s00[r]) : 0.f;
            float e01 = 0.f; (void)s01;
            float e10 = __builtin_amdgcn_exp2f(s10[r]);
            float e11 = keep ? __builtin_amdgcn_exp2f(s11[r]) : 0.f;
            lsum[0][r] += e00 + e01;
            lsum[1][r] += e10 + e11;
            uint32_t pk0 = __builtin_amdgcn_perm(
                __builtin_bit_cast(uint32_t, e01) + 0x8000u,
                __builtin_bit_cast(uint32_t, e00) + 0x8000u, 0x07060302u);
            uint32_t pk1 = __builtin_amdgcn_perm(
                __builtin_bit_cast(uint32_t, e11) + 0x8000u,
                __builtin_bit_cast(uint32_t, e10) + 0x8000u, 0x07060302u);
            P32[(wrow0 + r) * 20 + lrow]      = pk0;
            P32[(wrow0 + r + 16) * 20 + lrow] = pk1;
        }
        asm volatile("s_waitcnt lgkmcnt(0)" ::: "memory");

        bf16x8 pa0 = *(const bf16x8*)(Ps + (size_t)lrow * PST2 + quad * 8);
        bf16x8 pa1 = *(const bf16x8*)(Ps + (size_t)(16 + lrow) * PST2 + quad * 8);
        o[0][0] = __builtin_amdgcn_mfma_f32_16x16x32_bf16(pa0, bv0, o[0][0], 0, 0, 0);
        o[0][1] = __builtin_amdgcn_mfma_f32_16x16x32_bf16(pa0, bv1, o[0][1], 0, 0, 0);
        o[0][2] = __builtin_amdgcn_mfma_f32_16x16x32_bf16(pa0, bv2, o[0][2], 0, 0, 0);
        o[0][3] = __builtin_amdgcn_mfma_f32_16x16x32_bf16(pa0, bv3, o[0][3], 0, 0, 0);
        o[1][0] = __builtin_amdgcn_mfma_f32_16x16x32_bf16(pa1, bv0, o[1][0], 0, 0, 0);
        o[1][1] = __builtin_amdgcn_mfma_f32_16x16x32_bf16(pa1, bv1, o[1][1], 0, 0, 0);
        o[1][2] = __builtin_amdgcn_mfma_f32_16x16x32_bf16(pa1, bv2, o[1][2], 0, 0, 0);
        o[1][3] = __builtin_amdgcn_mfma_f32_16x16x32_bf16(pa1, bv3, o[1][3], 0, 0, 0);
    }

    const int b = bh >> 4, h = bh & 15;
    for (int t = 0; t < 2; ++t)
        for (int r = 0; r < 4; ++r) {
            float s = lsum[t][r];
            s += __shfl_xor(s, 1, 64);
            s += __shfl_xor(s, 2, 64);
            s += __shfl_xor(s, 4, 64);
            s += __shfl_xor(s, 8, 64);
            float inv = 1.0f / s;
            int q = q0 + t * 16 + quad * 4 + r;
            for (int dc = 0; dc < 4; ++dc)
                y[(size_t)(b * TT + q) * CC + h * HS + dc * 16 + lrow] = f2bf(o[t][dc][r] * inv);
        }
}

// ---------------------------------------------------------------- out GEMM (fp32 out + bias)
__global__ __launch_bounds__(256, 2) void k_gemm_out(const bf16_t* __restrict__ yin,
                                                     const bf16_t* __restrict__ Wt,
                                                     const float* __restrict__ bias,
                                                     float* __restrict__ out) {
    __shared__ bf16_t As[128 * 32];
    __shared__ bf16_t Bs[128 * 32];
    const int m0 = blockIdx.y * 128, n0 = blockIdx.x * 128;
    floatx4 acc[4][4];
    for (int i = 0; i < 4; ++i)
        for (int j = 0; j < 4; ++j)
            acc[i][j] = floatx4{0.f, 0.f, 0.f, 0.f};
    gemm_core(yin, Wt, As, Bs, m0, n0, CC, acc);

    const int tid = threadIdx.x, wave = tid >> 6, lane = tid & 63;
    const int quad = lane >> 4, lrow = lane & 15;
    const int wm = wave >> 1, wn = wave & 1;
    for (int i = 0; i < 4; ++i)
        for (int j = 0; j < 4; ++j) {
            int gn = n0 + wn * 64 + j * 16 + lrow;
            float bb = bias[gn];
            for (int r = 0; r < 4; ++r) {
                int gm = m0 + wm * 64 + i * 16 + quad * 4 + r;
                out[(size_t)gm * CC + gn] = acc[i][j][r] + bb;
            }
        }
}

// ---------------------------------------------------------------- launch
extern "C" void kernel_launch(void* const* d_in, const int* in_sizes, int n_in,
                              void* d_out, int out_size, void* d_ws, size_t ws_size,
                              hipStream_t stream) {
    (void)in_sizes; (void)n_in; (void)out_size; (void)ws_size;
    const float* x    = (const float*)d_in[0];  // [2,2048,1024] fp32
    const float* Wqkv = (const float*)d_in[1];  // [1024,3072]   fp32
    const float* Wout = (const float*)d_in[2];  // [1024,1024]   fp32
    const float* bout = (const float*)d_in[3];  // [1024]        fp32
    float* out = (float*)d_out;                 // [2,2048,1024] fp32

    bf16_t* xb  = (bf16_t*)d_ws;                        // [4096][1024]  8 MB
    bf16_t* Wt1 = xb + (size_t)MM * CC;                 // [3072][1024]  6 MB
    bf16_t* Wt2 = Wt1 + (size_t)N1 * CC;                // [1024][1024]  2 MB
    bf16_t* qb  = Wt2 + (size_t)CC * CC;                // [B,H,T,hs]    8 MB
    bf16_t* kb  = qb + (size_t)BB * HH * TT * HS;       // [B,H,T,hs]    8 MB
    bf16_t* vb  = kb + (size_t)BB * HH * TT * HS;       // [B,H,hs,T~]   8 MB (perm)
    bf16_t* yb  = vb + (size_t)BB * HH * TT * HS;       // [B,T,C] bf16  8 MB
    bf16_t* vn  = yb;   // natural V; lifetime ends at k_vperm, before yb born

    k_pack<<<dim3((size_t)MM * CC / (256 * 8)), 256, 0, stream>>>(x, xb);
    k_transpose<<<dim3(N1 / 32, CC / 32), dim3(32, 8), 0, stream>>>(Wqkv, Wt1, CC, N1);
    k_transpose<<<dim3(CC / 32, CC / 32), dim3(32, 8), 0, stream>>>(Wout, Wt2, CC, CC);
    k_gemm_qkv<<<dim3(N1 / 128, MM / 128), 256, 0, stream>>>(xb, Wt1, qb, kb, vn);
    k_vperm<<<dim3(32 * 32), 256, 0, stream>>>(vn, vb);
    k_attn<<<dim3(64 * 32), 64, 0, stream>>>(qb, kb, vb, yb);
    k_gemm_out<<<dim3(CC / 128, MM / 128), 256, 0, stream>>>(yb, Wt2, bout, out);
}

// Round 8
// 190.169 us; speedup vs baseline: 2.2370x; 1.1586x over previous
//
#include <hip/hip_runtime.h>
#include <cstdint>
#include <cstddef>

// Problem constants (from reference): B=2, T=2048, C=1024, H=16, hs=64
// Harness dtypes: inputs fp32, output fp32; internal compute bf16 MFMA.
#define BB 2
#define TT 2048
#define CC 1024
#define HH 16
#define HS 64
#define MM (BB*TT)      // 4096 rows
#define N1 (3*CC)       // 3072 qkv cols

// P-scratch row stride in elements (80 B/row)
#define PST2 40

// q prescale: hs^-0.5 * log2(e)  -> softmax_e(s) == softmax_2(s*log2e)
#define QSCALE 0.1803368801111243f

typedef __bf16 bf16_t;
typedef bf16_t bf16x8 __attribute__((ext_vector_type(8)));
typedef float  floatx4 __attribute__((ext_vector_type(4)));

__device__ __forceinline__ bf16_t f2bf(float f) {
    uint32_t u = __builtin_bit_cast(uint32_t, f);
    u += 0x7FFFu + ((u >> 16) & 1u);   // round-to-nearest-even
    unsigned short s = (unsigned short)(u >> 16);
    return __builtin_bit_cast(bf16_t, s);
}

__device__ __forceinline__ void load_lds16(const bf16_t* g, bf16_t* l) {
    __builtin_amdgcn_global_load_lds((__attribute__((address_space(1))) void*)g,
                                     (__attribute__((address_space(3))) void*)l,
                                     16, 0, 0);
}

// ---------------------------------------------------------------- pack x
__global__ __launch_bounds__(256) void k_pack(const float* __restrict__ src,
                                              bf16_t* __restrict__ dst) {
    size_t i = ((size_t)blockIdx.x * 256 + threadIdx.x) * 8;
    float4 a = *(const float4*)(src + i);
    float4 b = *(const float4*)(src + i + 4);
    bf16x8 o;
    o[0] = f2bf(a.x); o[1] = f2bf(a.y); o[2] = f2bf(a.z); o[3] = f2bf(a.w);
    o[4] = f2bf(b.x); o[5] = f2bf(b.y); o[6] = f2bf(b.z); o[7] = f2bf(b.w);
    *(bf16x8*)(dst + i) = o;
}

// ---------------------------------------------------------------- transpose+cvt
__global__ __launch_bounds__(256) void k_transpose(const float* __restrict__ src,
                                                   bf16_t* __restrict__ dst,
                                                   int R, int Ccol) {
    __shared__ bf16_t tile[32][33];
    int c0 = blockIdx.x * 32, r0 = blockIdx.y * 32;
    int tx = threadIdx.x, ty = threadIdx.y;
    for (int i = ty; i < 32; i += 8)
        tile[i][tx] = f2bf(src[(size_t)(r0 + i) * Ccol + c0 + tx]);
    __syncthreads();
    for (int i = ty; i < 32; i += 8)
        dst[(size_t)(c0 + i) * R + r0 + tx] = tile[tx][i];
}

// ---------------------------------------------------------------- GEMM core
__device__ __forceinline__ void gemm_core(const bf16_t* __restrict__ A,
                                          const bf16_t* __restrict__ Bt,
                                          bf16_t* As, bf16_t* Bs,
                                          int m0, int n0, int K,
                                          floatx4 acc[4][4]) {
    const int tid = threadIdx.x;
    const int wave = tid >> 6, lane = tid & 63;
    const int quad = lane >> 4, lrow = lane & 15;
    const int wm = wave >> 1, wn = wave & 1;
    const int lsub = lane >> 2;
    const int kc = lane & 3;

    for (int kk = 0; kk < K; kk += 32) {
        for (int s = 0; s < 2; ++s) {
            int rg = wave * 2 + s;
            const bf16_t* ga = A  + (size_t)(m0 + rg * 16 + lsub) * K + kk + kc * 8;
            const bf16_t* gb = Bt + (size_t)(n0 + rg * 16 + lsub) * K + kk + kc * 8;
            load_lds16(ga, As + rg * 512);
            load_lds16(gb, Bs + rg * 512);
        }
        __syncthreads();
        bf16x8 af[4], bfr[4];
        for (int i = 0; i < 4; ++i)
            af[i] = *(const bf16x8*)(As + (wm * 64 + i * 16 + lrow) * 32 + quad * 8);
        for (int j = 0; j < 4; ++j)
            bfr[j] = *(const bf16x8*)(Bs + (wn * 64 + j * 16 + lrow) * 32 + quad * 8);
        for (int i = 0; i < 4; ++i)
            for (int j = 0; j < 4; ++j)
                acc[i][j] = __builtin_amdgcn_mfma_f32_16x16x32_bf16(af[i], bfr[j], acc[i][j], 0, 0, 0);
        __syncthreads();
    }
}

// ---------------------------------------------------------------- QKV GEMM
__global__ __launch_bounds__(256, 2) void k_gemm_qkv(const bf16_t* __restrict__ x,
                                                     const bf16_t* __restrict__ Wt,
                                                     bf16_t* __restrict__ qb,
                                                     bf16_t* __restrict__ kb,
                                                     bf16_t* __restrict__ vn) {
    __shared__ bf16_t As[128 * 32];
    __shared__ bf16_t Bs[128 * 32];
    const int m0 = blockIdx.y * 128, n0 = blockIdx.x * 128;
    floatx4 acc[4][4];
    for (int i = 0; i < 4; ++i)
        for (int j = 0; j < 4; ++j)
            acc[i][j] = floatx4{0.f, 0.f, 0.f, 0.f};
    gemm_core(x, Wt, As, Bs, m0, n0, CC, acc);

    const int tid = threadIdx.x, wave = tid >> 6, lane = tid & 63;
    const int quad = lane >> 4, lrow = lane & 15;
    const int wm = wave >> 1, wn = wave & 1;
    for (int i = 0; i < 4; ++i)
        for (int j = 0; j < 4; ++j) {
            int gn = n0 + wn * 64 + j * 16 + lrow;
            int which = gn >> 10, c = gn & 1023, h = c >> 6, d = c & 63;
            for (int r = 0; r < 4; ++r) {
                int gm = m0 + wm * 64 + i * 16 + quad * 4 + r;
                int b = gm >> 11, t = gm & 2047;
                float val = acc[i][j][r];
                if (which == 0)
                    qb[((size_t)(b * HH + h) * TT + t) * HS + d] = f2bf(val * QSCALE);
                else if (which == 1)
                    kb[((size_t)(b * HH + h) * TT + t) * HS + d] = f2bf(val);
                else
                    vn[((size_t)(b * HH + h) * TT + t) * HS + d] = f2bf(val);
            }
        }
}

// ---------------------------------------------------------------- V permute
// vn[B,H,T,hs] -> vt[B,H,hs,T] with per-32 key interleave sigma(u)=(u&15)*2+(u>>4).
__global__ __launch_bounds__(256) void k_vperm(const bf16_t* __restrict__ vn,
                                               bf16_t* __restrict__ vt) {
    __shared__ bf16_t tile[64][72];
    const int tid = threadIdx.x;
    const int bh = blockIdx.x & 31, tb = blockIdx.x >> 5;
    const bf16_t* src = vn + ((size_t)bh * TT + tb * 64) * HS;

    for (int h = 0; h < 2; ++h) {
        int r = (tid >> 3) + h * 32;
        int c8 = (tid & 7) * 8;
        *(bf16x8*)(&tile[r][c8]) = *(const bf16x8*)(src + (size_t)r * HS + c8);
    }
    __syncthreads();

    bf16_t* dst = vt + (size_t)bh * HS * TT + tb * 64;
    const int a   = tid & 15;
    const int blk = ((tid >> 4) & 1) * 32;
    const int dg  = tid >> 5;
    for (int k = 0; k < 8; ++k) {
        int d = dg * 8 + k;
        uint32_t lo = (uint32_t)__builtin_bit_cast(unsigned short, tile[blk + a][d]);
        uint32_t hi = (uint32_t)__builtin_bit_cast(unsigned short, tile[blk + a + 16][d]);
        *(uint32_t*)(dst + (size_t)d * TT + blk + 2 * a) = lo | (hi << 16);
    }
}

// ---------------------------------------------------------------- attention
// 128-thr block = 2 waves = 2 consecutive 32-query tiles of one bh.
// Per 32-key tile the BLOCK cooperatively stages K (4KB contiguous) and
// V^T (64x64B rows) into padded LDS (K rows 144B, V rows 80B). Double-
// buffered, ONE barrier/iter; staging loads issued AFTER the barrier.
// Each wave has a PRIVATE 32-row P scratch (rows 0..15 = q-tile 0,
// rows 16..31 = q-tile 1) — R7 bug was sizing this 16 rows, aliasing the
// two waves' P buffers. No-max base-2 softmax; sigma-packed P.
__global__ __launch_bounds__(128, 2) void k_attn(const bf16_t* __restrict__ qb,
                                                 const bf16_t* __restrict__ kb,
                                                 const bf16_t* __restrict__ vt,
                                                 bf16_t* __restrict__ y) {
    __shared__ bf16_t Kb[2][32 * 72];   // key row stride 72 elem (144B)
    __shared__ bf16_t Vb[2][64 * 40];   // d row stride 40 elem (80B)
    __shared__ bf16_t Ps[2][32 * PST2]; // per-wave 32-row P scratch (FIX)
    const int tid = threadIdx.x;
    const int w = tid >> 6, lane = tid & 63;
    const int quad = lane >> 4, lrow = lane & 15;
    const int bh = blockIdx.x & 31;
    const int g = blockIdx.x >> 5;                 // 0..31
    const int t2 = g >> 3, u = g & 7;
    // CU gets g, g+8, g+16, g+24 -> qg quad {31-u, u, 23-u, 8+u}: const work
    const int qg = (t2 == 0) ? (31 - u) : (t2 == 1) ? u : (t2 == 2) ? (23 - u) : (8 + u);
    const int q0 = qg * 64 + w * 32;
    const int kend = qg * 2 + w + 1;               // this wave's key tiles
    const int ntmax = qg * 2 + 2;                  // block-uniform trip count

    const bf16_t* Qg = qb + (size_t)bh * TT * HS;
    const bf16_t* Kg = kb + (size_t)bh * TT * HS;
    const bf16_t* Vg = vt + (size_t)bh * HS * TT;

    // staging coords: K 4KB = 128 thr x 32B; V 64 rows x 64B = 128 thr x 32B
    const int skey = tid >> 2, scol = (tid & 3) * 16;
    const int svrow = tid >> 1, svcol = (tid & 1) * 16;

    bf16x8 kra, krb, vra, vrb;
    {   // prestage tile 0
        const bf16_t* gk = Kg + (size_t)skey * HS + scol;
        kra = *(const bf16x8*)(gk);
        krb = *(const bf16x8*)(gk + 8);
        const bf16_t* gv = Vg + (size_t)svrow * TT + svcol;
        vra = *(const bf16x8*)(gv);
        vrb = *(const bf16x8*)(gv + 8);
        *(bf16x8*)(&Kb[0][skey * 72 + scol])     = kra;
        *(bf16x8*)(&Kb[0][skey * 72 + scol + 8]) = krb;
        *(bf16x8*)(&Vb[0][svrow * 40 + svcol])     = vra;
        *(bf16x8*)(&Vb[0][svrow * 40 + svcol + 8]) = vrb;
    }

    bf16x8 aq[2][2];
    for (int tq = 0; tq < 2; ++tq)
        for (int c = 0; c < 2; ++c)
            aq[tq][c] = *(const bf16x8*)(Qg + (size_t)(q0 + tq * 16 + lrow) * HS + c * 32 + quad * 8);

    floatx4 o[2][4];
    for (int tq = 0; tq < 2; ++tq)
        for (int dc = 0; dc < 4; ++dc) o[tq][dc] = floatx4{0.f, 0.f, 0.f, 0.f};
    float lsum[2][4] = {{0.f,0.f,0.f,0.f},{0.f,0.f,0.f,0.f}};

    uint32_t* P32 = (uint32_t*)(&Ps[w][0]);
    const bf16_t* Pr = &Ps[w][0];
    const int wrow0 = quad * 4;

    for (int t = 0; t < ntmax; ++t) {
        __syncthreads();   // buf[t&1] (written at end of t-1 / prestage) visible
        if (t + 1 < ntmax) {   // issue next-tile staging loads (post-barrier!)
            const bf16_t* gk = Kg + (size_t)((t + 1) * 32 + skey) * HS + scol;
            kra = *(const bf16x8*)(gk);
            krb = *(const bf16x8*)(gk + 8);
            const bf16_t* gv = Vg + (size_t)svrow * TT + (t + 1) * 32 + svcol;
            vra = *(const bf16x8*)(gv);
            vrb = *(const bf16x8*)(gv + 8);
        }
        if (t < kend) {
            const bf16_t* Kt = &Kb[t & 1][0];
            const bf16_t* Vt = &Vb[t & 1][0];
            bf16x8 bk0 = *(const bf16x8*)(Kt + lrow * 72 + quad * 8);
            bf16x8 bk1 = *(const bf16x8*)(Kt + lrow * 72 + 32 + quad * 8);
            bf16x8 bk2 = *(const bf16x8*)(Kt + (16 + lrow) * 72 + quad * 8);
            bf16x8 bk3 = *(const bf16x8*)(Kt + (16 + lrow) * 72 + 32 + quad * 8);
            floatx4 s00 = floatx4{0.f,0.f,0.f,0.f}, s01 = s00, s10 = s00, s11 = s00;
            s00 = __builtin_amdgcn_mfma_f32_16x16x32_bf16(aq[0][0], bk0, s00, 0, 0, 0);
            s00 = __builtin_amdgcn_mfma_f32_16x16x32_bf16(aq[0][1], bk1, s00, 0, 0, 0);
            s01 = __builtin_amdgcn_mfma_f32_16x16x32_bf16(aq[0][0], bk2, s01, 0, 0, 0);
            s01 = __builtin_amdgcn_mfma_f32_16x16x32_bf16(aq[0][1], bk3, s01, 0, 0, 0);
            s10 = __builtin_amdgcn_mfma_f32_16x16x32_bf16(aq[1][0], bk0, s10, 0, 0, 0);
            s10 = __builtin_amdgcn_mfma_f32_16x16x32_bf16(aq[1][1], bk1, s10, 0, 0, 0);
            s11 = __builtin_amdgcn_mfma_f32_16x16x32_bf16(aq[1][0], bk2, s11, 0, 0, 0);
            s11 = __builtin_amdgcn_mfma_f32_16x16x32_bf16(aq[1][1], bk3, s11, 0, 0, 0);

            bf16x8 bv0 = *(const bf16x8*)(Vt + (0  + lrow) * 40 + quad * 8);
            bf16x8 bv1 = *(const bf16x8*)(Vt + (16 + lrow) * 40 + quad * 8);
            bf16x8 bv2 = *(const bf16x8*)(Vt + (32 + lrow) * 40 + quad * 8);
            bf16x8 bv3 = *(const bf16x8*)(Vt + (48 + lrow) * 40 + quad * 8);

            if (t < kend - 1) {            // unmasked tile
                for (int r = 0; r < 4; ++r) {
                    float e00 = __builtin_amdgcn_exp2f(s00[r]);
                    float e01 = __builtin_amdgcn_exp2f(s01[r]);
                    float e10 = __builtin_amdgcn_exp2f(s10[r]);
                    float e11 = __builtin_amdgcn_exp2f(s11[r]);
                    lsum[0][r] += e00 + e01;
                    lsum[1][r] += e10 + e11;
                    uint32_t pk0 = __builtin_amdgcn_perm(
                        __builtin_bit_cast(uint32_t, e01) + 0x8000u,
                        __builtin_bit_cast(uint32_t, e00) + 0x8000u, 0x07060302u);
                    uint32_t pk1 = __builtin_amdgcn_perm(
                        __builtin_bit_cast(uint32_t, e11) + 0x8000u,
                        __builtin_bit_cast(uint32_t, e10) + 0x8000u, 0x07060302u);
                    P32[(wrow0 + r) * 20 + lrow]      = pk0;
                    P32[(wrow0 + r + 16) * 20 + lrow] = pk1;
                }
            } else {                        // diagonal tile
                for (int r = 0; r < 4; ++r) {
                    bool keep = lrow <= quad * 4 + r;
                    float e00 = keep ? __builtin_amdgcn_exp2f(s00[r]) : 0.f;
                    float e01 = 0.f; (void)s01;
                    float e10 = __builtin_amdgcn_exp2f(s10[r]);
                    float e11 = keep ? __builtin_amdgcn_exp2f(s11[r]) : 0.f;
                    lsum[0][r] += e00 + e01;
                    lsum[1][r] += e10 + e11;
                    uint32_t pk0 = __builtin_amdgcn_perm(
                        __builtin_bit_cast(uint32_t, e01) + 0x8000u,
                        __builtin_bit_cast(uint32_t, e00) + 0x8000u, 0x07060302u);
                    uint32_t pk1 = __builtin_amdgcn_perm(
                        __builtin_bit_cast(uint32_t, e11) + 0x8000u,
                        __builtin_bit_cast(uint32_t, e10) + 0x8000u, 0x07060302u);
                    P32[(wrow0 + r) * 20 + lrow]      = pk0;
                    P32[(wrow0 + r + 16) * 20 + lrow] = pk1;
                }
            }
            asm volatile("s_waitcnt lgkmcnt(0)" ::: "memory");  // wave-local P RAW

            bf16x8 pa0 = *(const bf16x8*)(Pr + (size_t)lrow * PST2 + quad * 8);
            bf16x8 pa1 = *(const bf16x8*)(Pr + (size_t)(16 + lrow) * PST2 + quad * 8);
            o[0][0] = __builtin_amdgcn_mfma_f32_16x16x32_bf16(pa0, bv0, o[0][0], 0, 0, 0);
            o[0][1] = __builtin_amdgcn_mfma_f32_16x16x32_bf16(pa0, bv1, o[0][1], 0, 0, 0);
            o[0][2] = __builtin_amdgcn_mfma_f32_16x16x32_bf16(pa0, bv2, o[0][2], 0, 0, 0);
            o[0][3] = __builtin_amdgcn_mfma_f32_16x16x32_bf16(pa0, bv3, o[0][3], 0, 0, 0);
            o[1][0] = __builtin_amdgcn_mfma_f32_16x16x32_bf16(pa1, bv0, o[1][0], 0, 0, 0);
            o[1][1] = __builtin_amdgcn_mfma_f32_16x16x32_bf16(pa1, bv1, o[1][1], 0, 0, 0);
            o[1][2] = __builtin_amdgcn_mfma_f32_16x16x32_bf16(pa1, bv2, o[1][2], 0, 0, 0);
            o[1][3] = __builtin_amdgcn_mfma_f32_16x16x32_bf16(pa1, bv3, o[1][3], 0, 0, 0);
        }
        if (t + 1 < ntmax) {   // write next tile into the other buffer
            bf16_t* Kn = &Kb[(t + 1) & 1][0];
            bf16_t* Vn = &Vb[(t + 1) & 1][0];
            *(bf16x8*)(Kn + skey * 72 + scol)     = kra;
            *(bf16x8*)(Kn + skey * 72 + scol + 8) = krb;
            *(bf16x8*)(Vn + svrow * 40 + svcol)     = vra;
            *(bf16x8*)(Vn + svrow * 40 + svcol + 8) = vrb;
        }
    }

    const int b = bh >> 4, h = bh & 15;
    for (int tq = 0; tq < 2; ++tq)
        for (int r = 0; r < 4; ++r) {
            float s = lsum[tq][r];
            s += __shfl_xor(s, 1, 64);
            s += __shfl_xor(s, 2, 64);
            s += __shfl_xor(s, 4, 64);
            s += __shfl_xor(s, 8, 64);
            float inv = 1.0f / s;
            int q = q0 + tq * 16 + quad * 4 + r;
            for (int dc = 0; dc < 4; ++dc)
                y[(size_t)(b * TT + q) * CC + h * HS + dc * 16 + lrow] = f2bf(o[tq][dc][r] * inv);
        }
}

// ---------------------------------------------------------------- out GEMM (fp32 out + bias)
__global__ __launch_bounds__(256, 2) void k_gemm_out(const bf16_t* __restrict__ yin,
                                                     const bf16_t* __restrict__ Wt,
                                                     const float* __restrict__ bias,
                                                     float* __restrict__ out) {
    __shared__ bf16_t As[128 * 32];
    __shared__ bf16_t Bs[128 * 32];
    const int m0 = blockIdx.y * 128, n0 = blockIdx.x * 128;
    floatx4 acc[4][4];
    for (int i = 0; i < 4; ++i)
        for (int j = 0; j < 4; ++j)
            acc[i][j] = floatx4{0.f, 0.f, 0.f, 0.f};
    gemm_core(yin, Wt, As, Bs, m0, n0, CC, acc);

    const int tid = threadIdx.x, wave = tid >> 6, lane = tid & 63;
    const int quad = lane >> 4, lrow = lane & 15;
    const int wm = wave >> 1, wn = wave & 1;
    for (int i = 0; i < 4; ++i)
        for (int j = 0; j < 4; ++j) {
            int gn = n0 + wn * 64 + j * 16 + lrow;
            float bb = bias[gn];
            for (int r = 0; r < 4; ++r) {
                int gm = m0 + wm * 64 + i * 16 + quad * 4 + r;
                out[(size_t)gm * CC + gn] = acc[i][j][r] + bb;
            }
        }
}

// ---------------------------------------------------------------- launch
extern "C" void kernel_launch(void* const* d_in, const int* in_sizes, int n_in,
                              void* d_out, int out_size, void* d_ws, size_t ws_size,
                              hipStream_t stream) {
    (void)in_sizes; (void)n_in; (void)out_size; (void)ws_size;
    const float* x    = (const float*)d_in[0];  // [2,2048,1024] fp32
    const float* Wqkv = (const float*)d_in[1];  // [1024,3072]   fp32
    const float* Wout = (const float*)d_in[2];  // [1024,1024]   fp32
    const float* bout = (const float*)d_in[3];  // [1024]        fp32
    float* out = (float*)d_out;                 // [2,2048,1024] fp32

    bf16_t* xb  = (bf16_t*)d_ws;                        // [4096][1024]  8 MB
    bf16_t* Wt1 = xb + (size_t)MM * CC;                 // [3072][1024]  6 MB
    bf16_t* Wt2 = Wt1 + (size_t)N1 * CC;                // [1024][1024]  2 MB
    bf16_t* qb  = Wt2 + (size_t)CC * CC;                // [B,H,T,hs]    8 MB
    bf16_t* kb  = qb + (size_t)BB * HH * TT * HS;       // [B,H,T,hs]    8 MB
    bf16_t* vb  = kb + (size_t)BB * HH * TT * HS;       // [B,H,hs,T~]   8 MB (perm)
    bf16_t* yb  = vb + (size_t)BB * HH * TT * HS;       // [B,T,C] bf16  8 MB
    bf16_t* vn  = yb;   // natural V; lifetime ends at k_vperm, before yb born

    k_pack<<<dim3((size_t)MM * CC / (256 * 8)), 256, 0, stream>>>(x, xb);
    k_transpose<<<dim3(N1 / 32, CC / 32), dim3(32, 8), 0, stream>>>(Wqkv, Wt1, CC, N1);
    k_transpose<<<dim3(CC / 32, CC / 32), dim3(32, 8), 0, stream>>>(Wout, Wt2, CC, CC);
    k_gemm_qkv<<<dim3(N1 / 128, MM / 128), 256, 0, stream>>>(xb, Wt1, qb, kb, vn);
    k_vperm<<<dim3(32 * 32), 256, 0, stream>>>(vn, vb);
    k_attn<<<dim3(32 * 32), 128, 0, stream>>>(qb, kb, vb, yb);
    k_gemm_out<<<dim3(CC / 128, MM / 128), 256, 0, stream>>>(yb, Wt2, bout, out);
}